// Round 8
// baseline (182.321 us; speedup 1.0000x reference)
//
#include <hip/hip_runtime.h>

#define EPSC 1e-10f
#define BDIM 512
#define PDIM 1024
#define NDIM 1024
#define TDIM 32

typedef __attribute__((ext_vector_type(8))) short short8;
typedef __attribute__((ext_vector_type(4))) float f32x4;

static __device__ __forceinline__ short f2bf(float f) {
  unsigned u = __float_as_uint(f);
  unsigned r = (u + 0x7fffu + ((u >> 16) & 1u)) >> 16;
  return (short)r;
}

// DPP-based add of shifted value: v + dpp(v). bound_ctrl=1 -> invalid lanes read 0.
#define DPP_ADD(v, ctrl) \
  ((v) + __int_as_float(__builtin_amdgcn_update_dpp(0, __float_as_int(v), (ctrl), 0xf, 0xf, true)))

// sum over all 64 lanes; total lands in lane 63 (VALU pipe only)
static __device__ __forceinline__ float dpp_sum64_v(float v) {
  v = DPP_ADD(v, 0x111);  // row_shr:1
  v = DPP_ADD(v, 0x112);  // row_shr:2
  v = DPP_ADD(v, 0x114);  // row_shr:4
  v = DPP_ADD(v, 0x118);  // row_shr:8  -> lane 16r+15 = row sum
  v = DPP_ADD(v, 0x142);  // row_bcast15 -> lane 31/63 = half sums
  v = DPP_ADD(v, 0x143);  // row_bcast31 -> lane 63 = total
  return v;
}

// sum over lanes 0..31 (value duplicated across halves) -> uniform scalar
static __device__ __forceinline__ float dpp_sum32(float v) {
  v = DPP_ADD(v, 0x111);
  v = DPP_ADD(v, 0x112);
  v = DPP_ADD(v, 0x114);
  v = DPP_ADD(v, 0x118);
  v = DPP_ADD(v, 0x142);  // lane 31 = sum(0..31)
  return __int_as_float(__builtin_amdgcn_readlane(__float_as_int(v), 31));
}

// ============ merged conversion kernel ============
__global__ __launch_bounds__(256) void conv_kernel(
    const float* __restrict__ X, const float* __restrict__ W1, const float* __restrict__ W2,
    short* __restrict__ Xsw, short* __restrict__ T1, short* __restrict__ T2,
    float* __restrict__ pwsq)
{
  int tid = threadIdx.x;
  if (blockIdx.x < 256) {
    int i = blockIdx.x * 256 + tid;
    int m = i >> 7, c = i & 127;           // c = k/8
    const float* src = X + (size_t)m * 1024 + c * 8;
    float4 v0 = *(const float4*)src;
    float4 v1 = *(const float4*)(src + 4);
    short8 o;
    o[0] = f2bf(v0.x); o[1] = f2bf(v0.y); o[2] = f2bf(v0.z); o[3] = f2bf(v0.w);
    o[4] = f2bf(v1.x); o[5] = f2bf(v1.y); o[6] = f2bf(v1.z); o[7] = f2bf(v1.w);
    *(short8*)(Xsw + ((size_t)((m >> 4) * 32 + (c >> 2)) * 512) + (c & 3) * 128 + (m & 15) * 8) = o;
    return;
  }
  __shared__ float T[64][65];
  __shared__ float red[4];
  int wb = blockIdx.x - 256;
  int z = wb >> 8;
  int w = wb & 255;
  int r0 = (w >> 4) * 64;   // k rows
  int c0 = (w & 15) * 64;   // n cols
  const float* src = z ? W2 : W1;
  short* dst = z ? T2 : T1;
  float wsq = 0.0f;
#pragma unroll
  for (int i = 0; i < 4; ++i) {
    int row = (tid >> 4) + i * 16;
    int col = (tid & 15) << 2;
    float4 v = *(const float4*)(src + (size_t)(r0 + row) * NDIM + c0 + col);
    T[row][col + 0] = v.x; T[row][col + 1] = v.y; T[row][col + 2] = v.z; T[row][col + 3] = v.w;
    wsq = fmaf(v.x, v.x, wsq); wsq = fmaf(v.y, v.y, wsq);
    wsq = fmaf(v.z, v.z, wsq); wsq = fmaf(v.w, v.w, wsq);
  }
  __syncthreads();
  int nl = tid >> 2;              // 0..63
  int kb = (tid & 3) << 4;        // 0,16,32,48
  int ng = c0 + nl;
  int nt = ng >> 4, rn = ng & 15;
#pragma unroll
  for (int h = 0; h < 2; ++h) {
    int kg = r0 + kb + 8 * h;
    int kc = kg >> 5, q = (kg >> 3) & 3;
    short8 o;
#pragma unroll
    for (int e = 0; e < 8; ++e) o[e] = f2bf(T[kb + 8 * h + e][nl]);
    *(short8*)(dst + ((size_t)(nt * 32 + kc) * 512) + q * 128 + rn * 8) = o;
  }
#pragma unroll
  for (int d = 32; d >= 1; d >>= 1) wsq += __shfl_xor(wsq, d);
  if ((tid & 63) == 0) red[tid >> 6] = wsq;
  __syncthreads();
  if (tid == 0) pwsq[wb] = red[0] + red[1] + red[2] + red[3];
}

// ============ gemm1: a = relu(x@w_enc + b); Absw (frag-swizzled bf16); U[n][b] ============
__global__ __launch_bounds__(256) void gemm1_mfma(
    const short* __restrict__ Xsw, const short* __restrict__ Wsw,
    const float* __restrict__ bias, const float* __restrict__ centers,
    short* __restrict__ Absw, float* __restrict__ U, int* __restrict__ ticket)
{
  __shared__ float T2s[32][36];
  int tid = threadIdx.x;
  if (blockIdx.x == 0 && blockIdx.y == 0 && tid == 0) *ticket = 0;
  int lane = tid & 63, wid = tid >> 6;
  int wy = wid >> 1, wx = wid & 1;
  int mt = blockIdx.y * 2 + wy;
  int nt = blockIdx.x * 2 + wx;
  const short* ap = Xsw + (size_t)mt * 16384 + lane * 8;
  const short* bp = Wsw + (size_t)nt * 16384 + lane * 8;
  f32x4 acc = {0.f, 0.f, 0.f, 0.f};
#pragma unroll 8
  for (int kc = 0; kc < 32; ++kc) {
    short8 a = *(const short8*)(ap + kc * 512);
    short8 b = *(const short8*)(bp + kc * 512);
    acc = __builtin_amdgcn_mfma_f32_16x16x32_bf16(a, b, acc, 0, 0, 0);
  }
  int q = lane >> 4, r = lane & 15;
  int nn = nt * 16 + r;
  float bi = bias[nn];
  float c0 = centers[0];
  float invw = 1.0f / (centers[1] - centers[0]);
  short* abase = Absw + ((size_t)(mt * 32 + (nn >> 5)) * 512) + ((nn >> 3) & 3) * 128 + (nn & 7);
#pragma unroll
  for (int rr = 0; rr < 4; ++rr) {
    int rm = q * 4 + rr;                 // mm & 15
    float a = fmaxf(acc[rr] + bi, 0.0f);
    abase[rm * 8] = f2bf(a);
    T2s[wx * 16 + r][wy * 16 + rm] = (2.0f / (1.0f + __expf(-a)) - 1.0f - c0) * invw;
  }
  __syncthreads();
  int row = tid >> 3;            // n-local 0..31
  int col4 = (tid & 7) << 2;     // b-local
  float4 uv = make_float4(T2s[row][col4], T2s[row][col4 + 1], T2s[row][col4 + 2], T2s[row][col4 + 3]);
  *(float4*)(U + (size_t)(blockIdx.x * 32 + row) * BDIM + blockIdx.y * 32 + col4) = uv;
}

// ============ gemm2: x_hat = a@w_dec + b_dec; per-block recon partials ============
__global__ __launch_bounds__(256) void gemm2_mfma(
    const short* __restrict__ Absw, const short* __restrict__ Wdsw,
    const float* __restrict__ bias, const float* __restrict__ X,
    float* __restrict__ out, float* __restrict__ precon)
{
  __shared__ float red[4];
  int tid = threadIdx.x;
  int lane = tid & 63, wid = tid >> 6;
  int wy = wid >> 1, wx = wid & 1;
  int mt = blockIdx.y * 2 + wy;
  int nt = blockIdx.x * 2 + wx;
  const short* ap = Absw + (size_t)mt * 16384 + lane * 8;
  const short* bp = Wdsw + (size_t)nt * 16384 + lane * 8;
  f32x4 acc = {0.f, 0.f, 0.f, 0.f};
#pragma unroll 8
  for (int kc = 0; kc < 32; ++kc) {
    short8 a = *(const short8*)(ap + kc * 512);
    short8 b = *(const short8*)(bp + kc * 512);
    acc = __builtin_amdgcn_mfma_f32_16x16x32_bf16(a, b, acc, 0, 0, 0);
  }
  int q = lane >> 4, r = lane & 15;
  int nn = nt * 16 + r;
  float bi = bias[nn];
  float local = 0.0f;
#pragma unroll
  for (int rr = 0; rr < 4; ++rr) {
    int mm = mt * 16 + q * 4 + rr;
    float xh = acc[rr] + bi;
    out[(size_t)mm * PDIM + nn] = xh;
    float d = xh - X[(size_t)mm * PDIM + nn];
    local = fmaf(d, d, local);
  }
#pragma unroll
  for (int d = 32; d >= 1; d >>= 1) local += __shfl_xor(local, d);
  if ((tid & 63) == 0) red[tid >> 6] = local;
  __syncthreads();
  if (tid == 0) precon[blockIdx.y * 32 + blockIdx.x] = red[0] + red[1] + red[2] + red[3];
}

// ============ MLE: 4 waves per neuron (2 samples/lane), DPP trees + tiny LDS combine ============
// 1024 blocks x 256 threads -> 4096 waves = 4 waves/SIMD (latency overlap).
// Per wave per step: softmax via DPP, 4 pi-gathers, 17-bin register network (2 samples),
// DPP tree -> lane 63 writes 17 partials to parity-buffered LDS, 1 barrier, theta-lanes
// read 4 partials. S == 512.0 analytically (p >> eps).
__global__ __launch_bounds__(256) void mle_kernel(
    const float* __restrict__ U, const float* __restrict__ thetas,
    float* __restrict__ ent_out, const float* __restrict__ precon,
    const float* __restrict__ pwsq, int* __restrict__ ticket, float* __restrict__ out)
{
  int n = blockIdx.x;
  int tid = threadIdx.x;
  int lane = tid & 63, w = tid >> 6;
  int t2 = lane & 31;
  __shared__ float buf[2][72];
  __shared__ float entp[4];
  __shared__ int tick_s;

  // ---- 2 samples per lane ----
  float2 uv2 = *(const float2*)(U + (size_t)n * BDIM + w * 128 + lane * 2);
  float uu[2] = {uv2.x, uv2.y};
  float f[2]; int jl[2];             // jl = j - 15 in [0,15]
#pragma unroll
  for (int i = 0; i < 2; ++i) {
    int j = (int)uu[i];
    if (j > 30) j = 30;
    if (j < 15) j = 15;
    f[i] = uu[i] - (float)j;
    jl[i] = j - 15;
  }
  float th = thetas[(size_t)n * TDIM + t2];   // duplicated across halves & waves

#pragma unroll 1
  for (int step = 0; step < 15; ++step) {
    float e = __expf(th);
    float se = dpp_sum32(e);
    float pv = e * __builtin_amdgcn_rcpf(se);

    float pj[2], pj1[2];
#pragma unroll
    for (int i = 0; i < 2; ++i) { pj[i] = __shfl(pv, jl[i] + 15); pj1[i] = __shfl(pv, jl[i] + 16); }

    float w0[2], w1[2];
#pragma unroll
    for (int i = 0; i < 2; ++i) {
      float p = fmaf(f[i], pj1[i] - pj[i], pj[i]);
      float r = __builtin_amdgcn_rcpf(p + EPSC);
      w0[i] = (1.0f - f[i]) * r;
      w1[i] = f[i] * r;
    }

    float bins[17];
#pragma unroll
    for (int t = 0; t < 17; ++t) bins[t] = 0.0f;
#pragma unroll
    for (int i = 0; i < 2; ++i) {
#pragma unroll
      for (int t = 0; t < 17; ++t)
        bins[t] += (jl[i] == t) ? w0[i] : ((jl[i] == t - 1) ? w1[i] : 0.0f);
    }

#pragma unroll
    for (int t = 0; t < 17; ++t) bins[t] = dpp_sum64_v(bins[t]);   // lane 63 holds totals

    int par = step & 1;
    if (lane == 63) {
#pragma unroll
      for (int t = 0; t < 17; ++t) buf[par][w * 17 + t] = bins[t];
    }
    __syncthreads();

    float sv = 0.0f;
    if (t2 >= 15) {
      int b = t2 - 15;
      sv = buf[par][b] + buf[par][17 + b] + buf[par][34 + b] + buf[par][51 + b];
    }
    th += 0.01f * pv * (sv - 512.0f);   // S = sum(p/(p+eps)) == 512 to ~1e-7 rel
  }

  // ---- final softmax + entropy (per-wave partial over 128 samples) ----
  float e = __expf(th);
  float se = dpp_sum32(e);
  float pv = e * __builtin_amdgcn_rcpf(se);
  float ent = 0.0f;
#pragma unroll
  for (int i = 0; i < 2; ++i) {
    float pj  = __shfl(pv, jl[i] + 15);
    float pj1 = __shfl(pv, jl[i] + 16);
    float p = fmaf(f[i], pj1 - pj, pj);
    ent = fmaf(p, __logf(p + EPSC), ent);
  }
  ent = dpp_sum64_v(ent);
  if (lane == 63) entp[w] = ent;
  __syncthreads();
  if (tid == 0) ent_out[n] = -(entp[0] + entp[1] + entp[2] + entp[3]);

  // ---- last-block finalize ----
  __threadfence();
  if (tid == 0) tick_s = atomicAdd(ticket, 1);
  __syncthreads();
  if (tick_s == NDIM - 1) {
    __threadfence();
    const volatile float* ev = (const volatile float*)ent_out;
    float acc = 0.0f;
#pragma unroll
    for (int i = 0; i < 4; i++) acc += 0.01f * ev[tid + i * 256];
#pragma unroll
    for (int i = 0; i < 2; i++) acc += (0.5f / (float)BDIM) * precon[tid + i * 256];
#pragma unroll
    for (int i = 0; i < 2; i++) acc += 0.00025f * pwsq[tid + i * 256];
#pragma unroll
    for (int d = 32; d >= 1; d >>= 1) acc += __shfl_xor(acc, d);
    if (lane == 0) entp[w] = acc;
    __syncthreads();
    if (tid == 0) out[(size_t)BDIM * PDIM + NDIM] = entp[0] + entp[1] + entp[2] + entp[3];
  }
}

extern "C" void kernel_launch(void* const* d_in, const int* in_sizes, int n_in,
                              void* d_out, int out_size, void* d_ws, size_t ws_size,
                              hipStream_t stream) {
  (void)in_sizes; (void)n_in; (void)out_size; (void)ws_size;
  const float* x       = (const float*)d_in[0];
  const float* w_enc   = (const float*)d_in[1];
  const float* b_enc   = (const float*)d_in[2];
  const float* w_dec   = (const float*)d_in[3];
  const float* b_dec   = (const float*)d_in[4];
  const float* thetas  = (const float*)d_in[5];
  const float* centers = (const float*)d_in[6];
  float* out = (float*)d_out;

  char* ws = (char*)d_ws;
  short* Xsw    = (short*)(ws);                       // 1 MB
  short* Wsw    = (short*)(ws + (1 << 20));           // 2 MB
  short* Wdsw   = (short*)(ws + (3 << 20));           // 2 MB
  short* Absw   = (short*)(ws + (5 << 20));           // 1 MB
  float* U      = (float*)(ws + (6 << 20));           // 2 MB
  float* precon = (float*)(ws + (8 << 20));           // 2 KB
  float* pwsq   = (float*)(ws + (8 << 20) + 4096);    // 2 KB
  int*   ticket = (int*)(ws + (8 << 20) + 8192);      // 4 B
  float* ent_out = out + (size_t)BDIM * PDIM;

  hipLaunchKernelGGL(conv_kernel, dim3(768), dim3(256), 0, stream,
                     x, w_enc, w_dec, Xsw, Wsw, Wdsw, pwsq);
  hipLaunchKernelGGL(gemm1_mfma, dim3(32, 16), dim3(256), 0, stream,
                     Xsw, Wsw, b_enc, centers, Absw, U, ticket);
  hipLaunchKernelGGL(gemm2_mfma, dim3(32, 16), dim3(256), 0, stream,
                     Absw, Wdsw, b_dec, x, out, precon);
  hipLaunchKernelGGL(mle_kernel, dim3(NDIM), dim3(256), 0, stream,
                     U, thetas, ent_out, precon, pwsq, ticket, out);
}